// Round 2
// baseline (125.735 us; speedup 1.0000x reference)
//
#include <hip/hip_runtime.h>

#define CH 30
#define CELLS 49
#define ROWF 1470          // floats per batch row
#define RPW 2              // rows per wave (2*5880B = 16B-aligned region)
#define WPB 4              // waves per block
#define RPB 8              // rows per block
#define NPAIR 735          // float2 pairs per row
#define NQ4 735            // float4 quads per 2-row region
#define ITS 12             // ceil(735/64) quads per lane, fully hoisted

__device__ __forceinline__ float waveReduce(float v) {
    #pragma unroll
    for (int o = 32; o > 0; o >>= 1) v += __shfl_xor(v, o, 64);
    return v;
}

// One wave per PAIR of batch rows (float4-aligned streaming), 4 waves/block.
// No mid-kernel __syncthreads: boxS/clist are per-wave slices; wave lockstep +
// compiler lgkmcnt waits cover LDS write->read. Single barrier for block reduce.
__global__ __launch_bounds__(256) void yolo_main(const float* __restrict__ pred,
                                                 const float* __restrict__ targ,
                                                 float* __restrict__ ws, int B,
                                                 int NB) {
    const int w = threadIdx.x >> 6;
    const int lane = threadIdx.x & 63;
    const int r0 = (blockIdx.x * WPB + w) * RPW;

    __shared__ float4 boxS[WPB][2 * CELLS];  // pred boxes xyxy (broadcast reads)
    __shared__ int clist[WPB][CELLS];
    __shared__ float sred[WPB][3];

    float cls = 0.f, objc = 0.f, coord = 0.f;

    if (r0 < B) {                            // wave-uniform
        const int nrows = (B - r0) >= RPW ? RPW : 1;
        const float* P = pred + (size_t)r0 * ROWF;
        const float* T = targ + (size_t)r0 * ROWF;
        unsigned long long m[2] = {0ull, 0ull};

        if (nrows == 2) {
            const float4* P4 = (const float4*)P;
            const float4* T4 = (const float4*)T;

            // ---- conf loads first (ballot dependency), then the full stream ----
            const int cl = lane < CELLS ? lane : CELLS - 1;
            const float conf0 = T[cl * CH + 4];
            const float conf1 = T[ROWF + cl * CH + 4];

            float4 pv[ITS], tv[ITS];
            #pragma unroll
            for (int it = 0; it < ITS; ++it) {
                const int j = lane + it * 64;
                const int jc = j < NQ4 ? j : NQ4 - 1;   // clamp, gate at consume
                pv[it] = P4[jc];
                tv[it] = T4[jc];
            }

            const bool o0 = (lane < CELLS) && (conf0 > 0.f);
            const bool o1 = (lane < CELLS) && (conf1 > 0.f);
            m[0] = __ballot(o0);
            m[1] = __ballot(o1);

            // ---- branch-free consume: each float4 = two channel-pairs ----
            #pragma unroll
            for (int it = 0; it < ITS; ++it) {
                const int j = lane + it * 64;
                const bool valid = j < NQ4;
                #pragma unroll
                for (int k = 0; k < 2; ++k) {
                    const int q = 2 * j + k;            // pair index in 2-row stream
                    const int row = q >= NPAIR ? 1 : 0;
                    const int pr = q - row * NPAIR;     // pair index within row
                    const int cell = (pr * 17477) >> 18;   // pr/15 for pr<=767
                    const int ch0 = 2 * (pr - cell * 15);  // even channel of pair
                    const float wobj = (float)((m[row] >> cell) & 1ull);
                    const float px = k ? pv[it].z : pv[it].x;
                    const float py = k ? pv[it].w : pv[it].y;
                    const float tx = k ? tv[it].z : tv[it].x;
                    const float ty = k ? tv[it].w : tv[it].y;
                    const float dx = px - tx, dy = py - ty;
                    // class loss: channels 10..29, obj cells only
                    cls += (valid && ch0 >= 10) ? wobj * (dx * dx + dy * dy) : 0.f;
                    // noobj conf loss (x0.5 folded): ch4 + ch9
                    const float nn = (ch0 == 4 ? dx * dx : 0.f)
                                   + (ch0 == 8 ? dy * dy : 0.f);
                    objc += valid ? 0.5f * (1.f - wobj) * nn : 0.f;
                }
            }
        } else {
            // ---- fallback: single trailing row (never hit for even B) ----
            const float2* P2 = (const float2*)P;
            const float2* T2 = (const float2*)T;
            const int cl = lane < CELLS ? lane : CELLS - 1;
            const float conf = T[cl * CH + 4];
            const bool isObj = (lane < CELLS) && (conf > 0.f);
            m[0] = __ballot(isObj);
            for (int j = lane; j < NPAIR; j += 64) {
                const float2 pq = P2[j], tq = T2[j];
                const int cell = (j * 17477) >> 18;
                const int ch0 = 2 * (j - cell * 15);
                const float wobj = (float)((m[0] >> cell) & 1ull);
                const float dx = pq.x - tq.x, dy = pq.y - tq.y;
                cls += (ch0 >= 10) ? wobj * (dx * dx + dy * dy) : 0.f;
                const float nn = (ch0 == 4 ? dx * dx : 0.f)
                               + (ch0 == 8 ? dy * dy : 0.f);
                objc += 0.5f * (1.f - wobj) * nn;
            }
        }

        // ---- box/IoU phase, one row at a time (wave-uniform trip counts) ----
        for (int rr = 0; rr < nrows; ++rr) {
            const unsigned long long mask = m[rr];
            const int nBox = 2 * __popcll(mask);
            if (nBox == 0) continue;                    // wave-uniform
            const float* Pr = P + rr * ROWF;
            const float* Tr = T + rr * ROWF;

            const bool isObj = (lane < CELLS) && ((mask >> lane) & 1ull);
            if (isObj) clist[w][__popcll(mask & ((1ull << lane) - 1ull))] = lane;

            // masked pred boxes -> xyxy in LDS (global reads are L1-warm)
            for (int e = lane; e < nBox; e += 64) {
                const int c = clist[w][e >> 1];
                const float* pb = Pr + c * CH + (e & 1) * 5;
                const float cx = pb[0], cy = pb[1], bw = pb[2], bh = pb[3];
                boxS[w][e] = make_float4(cx - 0.5f * bw, cy - 0.5f * bh,
                                         cx + 0.5f * bw, cy + 0.5f * bh);
            }

            // per masked target box: max IoU over masked pred boxes; losses
            for (int e = lane; e < nBox; e += 64) {
                const int c = clist[w][e >> 1];
                const float* tb = Tr + c * CH + (e & 1) * 5;
                const float tcx = tb[0], tcy = tb[1], tw = tb[2], th = tb[3];
                const float tx1 = tcx - 0.5f * tw, ty1 = tcy - 0.5f * th;
                const float tx2 = tcx + 0.5f * tw, ty2 = tcy + 0.5f * th;
                const float ta = (tx2 - tx1) * (ty2 - ty1);
                float maxiou = 0.f;
                for (int i = 0; i < nBox; ++i) {
                    const float4 pb4 = boxS[w][i];      // wave-uniform = broadcast
                    const float lx = fmaxf(pb4.x, tx1), ly = fmaxf(pb4.y, ty1);
                    const float rx = fminf(pb4.z, tx2), ry = fminf(pb4.w, ty2);
                    const float iw = fmaxf(rx - lx, 0.f), ih = fmaxf(ry - ly, 0.f);
                    const float inter = iw * ih;
                    const float pa = (pb4.z - pb4.x) * (pb4.w - pb4.y);
                    const float un = pa + ta - inter;
                    const float iou = inter / (un > 0.f ? un : 1.f);
                    maxiou = fmaxf(maxiou, iou);
                }
                if (maxiou != 0.f) {                    // cmask
                    const float* pb = Pr + c * CH + (e & 1) * 5;
                    const float dcx = pb[0] - tcx, dcy = pb[1] - tcy;
                    coord += dcx * dcx + dcy * dcy;
                    const float dw = sqrtf(pb[2]) - sqrtf(tw);
                    const float dh = sqrtf(pb[3]) - sqrtf(th);
                    coord += dw * dw + dh * dh;
                    const float dc = pb[4] - tb[4];
                    objc += dc * dc;
                }
            }
        }
    }

    // ---- wave reduce, then block reduce (one barrier), one triple per block ----
    cls = waveReduce(cls); objc = waveReduce(objc); coord = waveReduce(coord);
    if (lane == 0) { sred[w][0] = cls; sred[w][1] = objc; sred[w][2] = coord; }
    __syncthreads();
    if (threadIdx.x == 0) {
        float C = 0.f, O = 0.f, X = 0.f;
        #pragma unroll
        for (int k = 0; k < WPB; ++k) { C += sred[k][0]; O += sred[k][1]; X += sred[k][2]; }
        ws[blockIdx.x] = C;
        ws[NB + blockIdx.x] = O;
        ws[2 * NB + blockIdx.x] = X;
    }
}

__global__ __launch_bounds__(1024) void yolo_reduce(const float* __restrict__ ws,
                                                    float* __restrict__ out,
                                                    int NB, float invB) {
    const int tid = threadIdx.x;
    const int w = tid >> 6, lane = tid & 63;
    float c = 0.f, o = 0.f, x = 0.f;
    for (int i = tid; i < NB; i += 1024) {
        c += ws[i];
        o += ws[NB + i];
        x += ws[2 * NB + i];
    }
    c = waveReduce(c); o = waveReduce(o); x = waveReduce(x);
    __shared__ float sred[16][3];
    if (lane == 0) { sred[w][0] = c; sred[w][1] = o; sred[w][2] = x; }
    __syncthreads();
    if (tid == 0) {
        float C = 0.f, O = 0.f, X = 0.f;
        #pragma unroll
        for (int k = 0; k < 16; ++k) { C += sred[k][0]; O += sred[k][1]; X += sred[k][2]; }
        const float bcls = C * invB;
        const float bobj = O * invB;          // noobj*0.5 folded upstream
        const float bcoord = X * 5.0f * invB; // COORD_LAMBDA
        out[0] = bcls + bobj + bcoord;
        out[1] = bcls;
        out[2] = bobj;
        out[3] = bcoord;
    }
}

extern "C" void kernel_launch(void* const* d_in, const int* in_sizes, int n_in,
                              void* d_out, int out_size, void* d_ws, size_t ws_size,
                              hipStream_t stream) {
    const float* pred = (const float*)d_in[0];
    const float* targ = (const float*)d_in[1];
    float* ws = (float*)d_ws;
    float* out = (float*)d_out;
    const int B = in_sizes[0] / ROWF;
    const int NB = (B + RPB - 1) / RPB;

    yolo_main<<<NB, 256, 0, stream>>>(pred, targ, ws, B, NB);
    yolo_reduce<<<1, 1024, 0, stream>>>(ws, out, NB, 1.0f / (float)B);
}

// Round 3
// 120.628 us; speedup vs baseline: 1.0423x; 1.0423x over previous
//
#include <hip/hip_runtime.h>

#define CH 30
#define CELLS 49
#define ROWF 1470          // floats per batch row
#define NPAIR 735          // float2 pairs per row
#define NQ4 735            // float4 quads per 2-row region
#define WPB 4              // waves per block
#define RPBLK 4            // rows per block = 2 regions x 2 rows
#define HITS 6             // quad-iterations per wave (half of a region)

__device__ __forceinline__ float waveReduce(float v) {
    #pragma unroll
    for (int o = 32; o > 0; o >>= 1) v += __shfl_xor(v, o, 64);
    return v;
}

// Two waves share one 2-row (float4-aligned) region, taking alternating
// 64-quad stripes: full 8 waves/SIMD occupancy AND dwordx4 loads. Depth-2
// rotating prefetch keeps exactly 2 loads in flight per wave (16 staging
// VGPRs) so the allocator cannot serialize the stream (R2 lesson: 96-reg
// hoist collapsed to 68 VGPRs = serialized loads). launch_bounds(256,8)
// pins VGPR<=64 for 8 waves/SIMD. No mid-kernel barrier: boxS/clist are
// per-wave slices; each wave box-phases one row of its region.
__global__ __launch_bounds__(256, 8) void yolo_main(const float* __restrict__ pred,
                                                    const float* __restrict__ targ,
                                                    float* __restrict__ ws, int B,
                                                    int NB) {
    const int w = threadIdx.x >> 6;
    const int lane = threadIdx.x & 63;
    const int h = w & 1;                         // half within the region
    const int r0 = blockIdx.x * RPBLK + (w >> 1) * 2;

    __shared__ float4 boxS[WPB][2 * CELLS];      // pred boxes xyxy (broadcast)
    __shared__ int clist[WPB][CELLS];
    __shared__ float sred[WPB][3];

    float cls = 0.f, objc = 0.f, coord = 0.f;

    if (r0 < B) {                                // wave-uniform
        const int nrows = (B - r0) >= 2 ? 2 : 1;
        const float* P = pred + (size_t)r0 * ROWF;
        const float* T = targ + (size_t)r0 * ROWF;
        unsigned long long m[2] = {0ull, 0ull};

        if (nrows == 2) {
            const float4* P4 = (const float4*)P;
            const float4* T4 = (const float4*)T;

            // ---- conf gathers (1 scattered dword load per row) issued first ----
            const int cl = lane < CELLS ? lane : CELLS - 1;
            const float conf0 = T[cl * CH + 4];
            const float conf1 = T[ROWF + cl * CH + 4];

            // ---- pipeline prologue: stripe 0 of this wave's half ----
            const int q0 = lane + h * 64;
            const int q0c = q0 < NQ4 ? q0 : NQ4 - 1;
            float4 pa = P4[q0c];
            float4 ta = T4[q0c];

            m[0] = __ballot((lane < CELLS) && (conf0 > 0.f));
            m[1] = __ballot((lane < CELLS) && (conf1 > 0.f));

            // ---- depth-2 rotating pipeline over this wave's 6 stripes ----
            #pragma unroll
            for (int it = 0; it < HITS; ++it) {
                float4 pb, tb;
                if (it + 1 < HITS) {
                    const int qn = lane + (2 * (it + 1) + h) * 64;
                    const int qc = qn < NQ4 ? qn : NQ4 - 1;
                    pb = P4[qc];
                    tb = T4[qc];
                }
                const int qq = lane + (2 * it + h) * 64;
                const bool valid = qq < NQ4;
                #pragma unroll
                for (int k = 0; k < 2; ++k) {
                    const int p = 2 * qq + k;            // pair idx in 2-row stream
                    const int row = p >= NPAIR ? 1 : 0;
                    const int pr = p - row * NPAIR;      // pair idx within row
                    const int cell = (pr * 17477) >> 18; // pr/15 (ok to pr<=767)
                    const int ch0 = 2 * (pr - cell * 15);
                    const float wobj = (float)((m[row] >> cell) & 1ull);
                    const float px = k ? pa.z : pa.x;
                    const float py = k ? pa.w : pa.y;
                    const float tx = k ? ta.z : ta.x;
                    const float ty = k ? ta.w : ta.y;
                    const float dx = px - tx, dy = py - ty;
                    // class loss: channels 10..29, obj cells only
                    cls += (valid && ch0 >= 10) ? wobj * (dx * dx + dy * dy) : 0.f;
                    // noobj conf loss (x0.5 folded): ch4 (.x) + ch9 (.y)
                    const float nn = (ch0 == 4 ? dx * dx : 0.f)
                                   + (ch0 == 8 ? dy * dy : 0.f);
                    objc += valid ? 0.5f * (1.f - wobj) * nn : 0.f;
                }
                if (it + 1 < HITS) { pa = pb; ta = tb; }
            }

            // ---- box/IoU phase: this wave handles row h of its region ----
            const unsigned long long mask = m[h];
            const int nBox = 2 * __popcll(mask);
            if (nBox) {                                  // wave-uniform
                const float* Pr = P + h * ROWF;
                const float* Tr = T + h * ROWF;
                const bool isObj = (lane < CELLS) && ((mask >> lane) & 1ull);
                if (isObj) clist[w][__popcll(mask & ((1ull << lane) - 1ull))] = lane;

                // masked pred boxes -> xyxy in LDS (global reads L1/L2-warm)
                for (int e = lane; e < nBox; e += 64) {
                    const int c = clist[w][e >> 1];
                    const float* pb = Pr + c * CH + (e & 1) * 5;
                    const float cx = pb[0], cy = pb[1], bw = pb[2], bh = pb[3];
                    boxS[w][e] = make_float4(cx - 0.5f * bw, cy - 0.5f * bh,
                                             cx + 0.5f * bw, cy + 0.5f * bh);
                }

                // per masked target box: max IoU over masked pred boxes; losses
                for (int e = lane; e < nBox; e += 64) {
                    const int c = clist[w][e >> 1];
                    const float* tb = Tr + c * CH + (e & 1) * 5;
                    const float tcx = tb[0], tcy = tb[1], tw = tb[2], th = tb[3];
                    const float tx1 = tcx - 0.5f * tw, ty1 = tcy - 0.5f * th;
                    const float tx2 = tcx + 0.5f * tw, ty2 = tcy + 0.5f * th;
                    const float ta2 = (tx2 - tx1) * (ty2 - ty1);
                    float maxiou = 0.f;
                    for (int i = 0; i < nBox; ++i) {
                        const float4 pb4 = boxS[w][i];   // uniform addr = broadcast
                        const float lx = fmaxf(pb4.x, tx1), ly = fmaxf(pb4.y, ty1);
                        const float rx = fminf(pb4.z, tx2), ry = fminf(pb4.w, ty2);
                        const float iw = fmaxf(rx - lx, 0.f), ih = fmaxf(ry - ly, 0.f);
                        const float inter = iw * ih;
                        const float pa2 = (pb4.z - pb4.x) * (pb4.w - pb4.y);
                        const float un = pa2 + ta2 - inter;
                        const float iou = inter / (un > 0.f ? un : 1.f);
                        maxiou = fmaxf(maxiou, iou);
                    }
                    if (maxiou != 0.f) {                 // cmask
                        const float* pb = Pr + c * CH + (e & 1) * 5;
                        const float dcx = pb[0] - tcx, dcy = pb[1] - tcy;
                        coord += dcx * dcx + dcy * dcy;
                        const float dw = sqrtf(pb[2]) - sqrtf(tw);
                        const float dh = sqrtf(pb[3]) - sqrtf(th);
                        coord += dw * dw + dh * dh;
                        const float dc = pb[4] - tb[4];
                        objc += dc * dc;
                    }
                }
            }
        } else if (h == 0) {
            // ---- fallback: single trailing row, h==0 wave only ----
            const float2* P2 = (const float2*)P;
            const float2* T2 = (const float2*)T;
            const int cl = lane < CELLS ? lane : CELLS - 1;
            const float conf = T[cl * CH + 4];
            const bool isObj = (lane < CELLS) && (conf > 0.f);
            const unsigned long long mask = __ballot(isObj);
            for (int j = lane; j < NPAIR; j += 64) {
                const float2 pq = P2[j], tq = T2[j];
                const int cell = (j * 17477) >> 18;
                const int ch0 = 2 * (j - cell * 15);
                const float wobj = (float)((mask >> cell) & 1ull);
                const float dx = pq.x - tq.x, dy = pq.y - tq.y;
                cls += (ch0 >= 10) ? wobj * (dx * dx + dy * dy) : 0.f;
                const float nn = (ch0 == 4 ? dx * dx : 0.f)
                               + (ch0 == 8 ? dy * dy : 0.f);
                objc += 0.5f * (1.f - wobj) * nn;
            }
            const int nBox = 2 * __popcll(mask);
            if (nBox) {
                if (isObj) clist[w][__popcll(mask & ((1ull << lane) - 1ull))] = lane;
                for (int e = lane; e < nBox; e += 64) {
                    const int c = clist[w][e >> 1];
                    const float* pb = P + c * CH + (e & 1) * 5;
                    const float cx = pb[0], cy = pb[1], bw = pb[2], bh = pb[3];
                    boxS[w][e] = make_float4(cx - 0.5f * bw, cy - 0.5f * bh,
                                             cx + 0.5f * bw, cy + 0.5f * bh);
                }
                for (int e = lane; e < nBox; e += 64) {
                    const int c = clist[w][e >> 1];
                    const float* tb = T + c * CH + (e & 1) * 5;
                    const float tcx = tb[0], tcy = tb[1], tw = tb[2], th = tb[3];
                    const float tx1 = tcx - 0.5f * tw, ty1 = tcy - 0.5f * th;
                    const float tx2 = tcx + 0.5f * tw, ty2 = tcy + 0.5f * th;
                    const float ta2 = (tx2 - tx1) * (ty2 - ty1);
                    float maxiou = 0.f;
                    for (int i = 0; i < nBox; ++i) {
                        const float4 pb4 = boxS[w][i];
                        const float lx = fmaxf(pb4.x, tx1), ly = fmaxf(pb4.y, ty1);
                        const float rx = fminf(pb4.z, tx2), ry = fminf(pb4.w, ty2);
                        const float iw = fmaxf(rx - lx, 0.f), ih = fmaxf(ry - ly, 0.f);
                        const float inter = iw * ih;
                        const float pa2 = (pb4.z - pb4.x) * (pb4.w - pb4.y);
                        const float un = pa2 + ta2 - inter;
                        const float iou = inter / (un > 0.f ? un : 1.f);
                        maxiou = fmaxf(maxiou, iou);
                    }
                    if (maxiou != 0.f) {
                        const float* pb = P + c * CH + (e & 1) * 5;
                        const float dcx = pb[0] - tcx, dcy = pb[1] - tcy;
                        coord += dcx * dcx + dcy * dcy;
                        const float dw = sqrtf(pb[2]) - sqrtf(tw);
                        const float dh = sqrtf(pb[3]) - sqrtf(th);
                        coord += dw * dw + dh * dh;
                        const float dc = pb[4] - tb[4];
                        objc += dc * dc;
                    }
                }
            }
        }
    }

    // ---- wave reduce, then block reduce (one barrier), one triple per block ----
    cls = waveReduce(cls); objc = waveReduce(objc); coord = waveReduce(coord);
    if (lane == 0) { sred[w][0] = cls; sred[w][1] = objc; sred[w][2] = coord; }
    __syncthreads();
    if (threadIdx.x == 0) {
        float C = 0.f, O = 0.f, X = 0.f;
        #pragma unroll
        for (int k = 0; k < WPB; ++k) { C += sred[k][0]; O += sred[k][1]; X += sred[k][2]; }
        ws[blockIdx.x] = C;
        ws[NB + blockIdx.x] = O;
        ws[2 * NB + blockIdx.x] = X;
    }
}

__global__ __launch_bounds__(1024) void yolo_reduce(const float* __restrict__ ws,
                                                    float* __restrict__ out,
                                                    int NB, float invB) {
    const int tid = threadIdx.x;
    const int w = tid >> 6, lane = tid & 63;
    float c = 0.f, o = 0.f, x = 0.f;
    for (int i = tid; i < NB; i += 1024) {
        c += ws[i];
        o += ws[NB + i];
        x += ws[2 * NB + i];
    }
    c = waveReduce(c); o = waveReduce(o); x = waveReduce(x);
    __shared__ float sred[16][3];
    if (lane == 0) { sred[w][0] = c; sred[w][1] = o; sred[w][2] = x; }
    __syncthreads();
    if (tid == 0) {
        float C = 0.f, O = 0.f, X = 0.f;
        #pragma unroll
        for (int k = 0; k < 16; ++k) { C += sred[k][0]; O += sred[k][1]; X += sred[k][2]; }
        const float bcls = C * invB;
        const float bobj = O * invB;          // noobj*0.5 folded upstream
        const float bcoord = X * 5.0f * invB; // COORD_LAMBDA
        out[0] = bcls + bobj + bcoord;
        out[1] = bcls;
        out[2] = bobj;
        out[3] = bcoord;
    }
}

extern "C" void kernel_launch(void* const* d_in, const int* in_sizes, int n_in,
                              void* d_out, int out_size, void* d_ws, size_t ws_size,
                              hipStream_t stream) {
    const float* pred = (const float*)d_in[0];
    const float* targ = (const float*)d_in[1];
    float* ws = (float*)d_ws;
    float* out = (float*)d_out;
    const int B = in_sizes[0] / ROWF;
    const int NB = (B + RPBLK - 1) / RPBLK;

    yolo_main<<<NB, 256, 0, stream>>>(pred, targ, ws, B, NB);
    yolo_reduce<<<1, 1024, 0, stream>>>(ws, out, NB, 1.0f / (float)B);
}